// Round 3
// baseline (1188.668 us; speedup 1.0000x reference)
//
#include <hip/hip_runtime.h>

// z <- tanh(z @ W^T + x), 50 fixed-point iterations. B=16384, D=512.
// Persistent-block: each block owns 64 rows of z for all iterations.
// z lives in LDS in MFMA B-fragment order (double-buffered, 2x64KB dynamic
// LDS) -> conflict-free ds_read_b128/ds_write_b64 with immediate offsets and
// ONE barrier per iteration. W is bf16 A-fragments in d_ws (L2-resident).
// x (pre-scaled by 2*log2e) lives in 64 VGPRs per lane for the whole run.
//
// launch_bounds(512,1): 128KB LDS already caps at 1 block/CU; the 512-thread
// block forces VGPR<=256 which fits the ~190-reg live set. (512,2) in the
// previous round capped VGPR at 128 -> scratch spills -> 1.9GB HBM traffic.

typedef short s8v   __attribute__((ext_vector_type(8)));   // 8 bf16 = 4 VGPRs
typedef float f32x16 __attribute__((ext_vector_type(16)));

#define BATCH 16384
#define DIM   512
#define TM    64
#define NITER 50
#define L2E2  2.8853900817779268f   // 2 * log2(e)

__device__ __forceinline__ unsigned short f2bf(float f) {
    unsigned int u = __float_as_uint(f);
    u += 0x7fffu + ((u >> 16) & 1u);          // round-to-nearest-even
    return (unsigned short)(u >> 16);
}

// arg is already v * 2*log2(e).  tanh = 1 - 2/(exp2(arg)+1).
// arg -> +inf: rcp(inf)=0 -> 1;  arg -> -inf: exp2->0 -> -1.  No clamp needed.
__device__ __forceinline__ float tanh_e(float arg) {
    float t = __builtin_amdgcn_exp2f(arg);
    float r = __builtin_amdgcn_rcpf(t + 1.0f);
    return fmaf(-2.0f, r, 1.0f);
}

__device__ __forceinline__ f32x16 zero16() {
    f32x16 v;
#pragma unroll
    for (int i = 0; i < 16; ++i) v[i] = 0.0f;
    return v;
}

// W (fp32 [512][512] row-major) -> bf16 A-fragments for v_mfma_f32_32x32x16_bf16.
// Granule tid = (jt*32 + ks)*64 + lane holds W[j = 32*jt + (lane&31)]
// [k = 16*ks + 8*(lane>>5) .. +8] as 16 B.
__global__ void wprep_kernel(const float* __restrict__ W, unsigned short* __restrict__ Wf) {
    int tid = blockIdx.x * blockDim.x + threadIdx.x;   // 0..32767
    int jt  = tid >> 11;
    int rem = tid & 2047;
    int ks  = rem >> 6;
    int L   = rem & 63;
    int j   = jt * 32 + (L & 31);
    int k   = ks * 16 + (L >> 5) * 8;
    const float* src = W + j * DIM + k;
    uint4 p;
    p.x = (unsigned)f2bf(src[0]) | ((unsigned)f2bf(src[1]) << 16);
    p.y = (unsigned)f2bf(src[2]) | ((unsigned)f2bf(src[3]) << 16);
    p.z = (unsigned)f2bf(src[4]) | ((unsigned)f2bf(src[5]) << 16);
    p.w = (unsigned)f2bf(src[6]) | ((unsigned)f2bf(src[7]) << 16);
    ((uint4*)Wf)[tid] = p;
}

__global__ __launch_bounds__(512, 1)
void fixpoint_kernel(const float* __restrict__ x,
                     const unsigned short* __restrict__ Wf,
                     float* __restrict__ out) {
    extern __shared__ unsigned short zb[];   // 2 buffers x 32768 bf16 (2x64KB)

    const int tid  = threadIdx.x;
    const int lane = tid & 63;
    const int w    = tid >> 6;        // wave 0..7, owns j-slab [64w, 64w+64)
    const int l31  = lane & 31;
    const int h    = lane >> 5;
    const int r0   = blockIdx.x * TM;

    // ---- preload x (pre-scaled) into regs: xr[rt][t], t = (jhalf<<2)|g ----
    float4 xr[2][8];
#pragma unroll
    for (int rt = 0; rt < 2; ++rt) {
        const float* xrow = x + (size_t)(r0 + rt * 32 + l31) * DIM;
#pragma unroll
        for (int t = 0; t < 8; ++t) {
            int j0 = w * 64 + (t >> 2) * 32 + (t & 3) * 8 + 4 * h;
            float4 v = *(const float4*)&xrow[j0];
            v.x *= L2E2; v.y *= L2E2; v.z *= L2E2; v.w *= L2E2;
            xr[rt][t] = v;
        }
    }

    // ---- iteration 1: z = tanh(x) into zb[0] (fragment layout) ----
#pragma unroll
    for (int rt = 0; rt < 2; ++rt)
#pragma unroll
        for (int t = 0; t < 8; ++t) {
            int j0 = w * 64 + (t >> 2) * 32 + (t & 3) * 8 + 4 * h;
            float4 a = xr[rt][t];
            float v0 = tanh_e(a.x), v1 = tanh_e(a.y);
            float v2 = tanh_e(a.z), v3 = tanh_e(a.w);
            uint2 p;
            p.x = ((unsigned)f2bf(v1) << 16) | f2bf(v0);
            p.y = ((unsigned)f2bf(v3) << 16) | f2bf(v2);
            int e = ((rt * 32 + (j0 >> 4)) * 64 + ((j0 >> 3) & 1) * 32 + l31) * 8 + (j0 & 7);
            *(uint2*)&zb[e] = p;
        }
    __syncthreads();

    const s8v* Wv = (const s8v*)Wf + w * 4096 + lane;   // this wave's A-slab

    for (int it = 0; it < NITER - 1; ++it) {
        const s8v* zcv = (const s8v*)(zb + (it & 1) * 32768) + lane;
        unsigned short* zn = zb + ((it + 1) & 1) * 32768;

        f32x16 acc00 = zero16(), acc01 = zero16(), acc10 = zero16(), acc11 = zero16();

#pragma unroll
        for (int ks = 0; ks < 32; ++ks) {
            s8v a0 = Wv[ks * 64];          // W rows [64w,64w+32)
            s8v a1 = Wv[ks * 64 + 2048];   // W rows [64w+32,64w+64)
            s8v b0 = zcv[ks * 64];         // z rows 0..31
            s8v b1 = zcv[ks * 64 + 2048];  // z rows 32..63
            acc00 = __builtin_amdgcn_mfma_f32_32x32x16_bf16(a0, b0, acc00, 0, 0, 0);
            acc01 = __builtin_amdgcn_mfma_f32_32x32x16_bf16(a0, b1, acc01, 0, 0, 0);
            acc10 = __builtin_amdgcn_mfma_f32_32x32x16_bf16(a1, b0, acc10, 0, 0, 0);
            acc11 = __builtin_amdgcn_mfma_f32_32x32x16_bf16(a1, b1, acc11, 0, 0, 0);
        }

        const bool last = (it == NITER - 2);

        // D[m=j][n=r]: col = lane&31 -> z-row; row = (reg&3)+8*(reg>>2)+4*h -> j
        auto epi = [&](const f32x16& acc, int tb, int rt) {
#pragma unroll
            for (int g = 0; g < 4; ++g) {
                int t  = tb + g;
                int j0 = w * 64 + tb * 8 + g * 8 + 4 * h;
                float4 a = xr[rt][t];
                float v0 = tanh_e(fmaf(acc[4 * g + 0], L2E2, a.x));
                float v1 = tanh_e(fmaf(acc[4 * g + 1], L2E2, a.y));
                float v2 = tanh_e(fmaf(acc[4 * g + 2], L2E2, a.z));
                float v3 = tanh_e(fmaf(acc[4 * g + 3], L2E2, a.w));
                uint2 p;
                p.x = ((unsigned)f2bf(v1) << 16) | f2bf(v0);
                p.y = ((unsigned)f2bf(v3) << 16) | f2bf(v2);
                int e = ((rt * 32 + (j0 >> 4)) * 64 + ((j0 >> 3) & 1) * 32 + l31) * 8 + (j0 & 7);
                *(uint2*)&zn[e] = p;
                if (last) {
                    float4 o; o.x = v0; o.y = v1; o.z = v2; o.w = v3;
                    *(float4*)&out[(size_t)(r0 + rt * 32 + l31) * DIM + j0] = o;
                }
            }
        };
        epi(acc00, 0, 0);
        epi(acc10, 4, 0);
        epi(acc01, 0, 1);
        epi(acc11, 4, 1);

        __syncthreads();   // writes to zn visible; next iter reads other buffer
    }
}

extern "C" void kernel_launch(void* const* d_in, const int* in_sizes, int n_in,
                              void* d_out, int out_size, void* d_ws, size_t ws_size,
                              hipStream_t stream) {
    const float* x = (const float*)d_in[0];   // [16384, 512] fp32
    const float* W = (const float*)d_in[1];   // [512, 512] fp32
    float* out = (float*)d_out;               // [16384, 512] fp32
    unsigned short* Wf = (unsigned short*)d_ws;

    hipFuncSetAttribute((const void*)fixpoint_kernel,
                        hipFuncAttributeMaxDynamicSharedMemorySize, 131072);
    wprep_kernel<<<128, 256, 0, stream>>>(W, Wf);
    fixpoint_kernel<<<BATCH / TM, 512, 131072, stream>>>(x, Wf, out);
}

// Round 5
// 739.077 us; speedup vs baseline: 1.6083x; 1.6083x over previous
//
#include <hip/hip_runtime.h>

// z <- tanh(z @ W^T + x), 50 fixed-point iterations. B=16384, D=512.
// Persistent-block: each block owns 64 rows of z for all iterations.
// z lives in a SINGLE static 64KB LDS buffer in MFMA B-fragment order
// (conflict-free ds_read_b128, immediate offsets), two barriers per
// iteration (read-phase / write-phase). W is bf16 A-fragments in d_ws.
// x is re-read from L2 every epilogue; opaque per-iteration offsets
// (empty asm) block LICM from hoisting the loop-invariant x/Wf loads
// into registers (rounds 2-4: hoist -> spill -> scratch traffic + the
// post-timing divergence). Static LDS, no hipFuncSetAttribute, no
// dynamic-LDS path: keep the graph-captured launch boring.

typedef short s8v   __attribute__((ext_vector_type(8)));   // 8 bf16 = 4 VGPRs
typedef float f32x16 __attribute__((ext_vector_type(16)));

#define BATCH 16384
#define DIM   512
#define TM    64
#define NITER 50
#define L2E2  2.8853900817779268f   // 2 * log2(e)

__device__ __forceinline__ unsigned short f2bf(float f) {
    unsigned int u = __float_as_uint(f);
    u += 0x7fffu + ((u >> 16) & 1u);          // round-to-nearest-even
    return (unsigned short)(u >> 16);
}

// arg is already v * 2*log2(e).  tanh = 1 - 2/(exp2(arg)+1).
// arg -> +inf: rcp(inf)=0 -> 1;  arg -> -inf: exp2->0 -> -1.  No clamp needed.
__device__ __forceinline__ float tanh_e(float arg) {
    float t = __builtin_amdgcn_exp2f(arg);
    float r = __builtin_amdgcn_rcpf(t + 1.0f);
    return fmaf(-2.0f, r, 1.0f);
}

__device__ __forceinline__ f32x16 zero16() {
    f32x16 v;
#pragma unroll
    for (int i = 0; i < 16; ++i) v[i] = 0.0f;
    return v;
}

// W (fp32 [512][512] row-major) -> bf16 A-fragments for v_mfma_f32_32x32x16_bf16.
// Granule tid = (jt*32 + ks)*64 + lane holds W[j = 32*jt + (lane&31)]
// [k = 16*ks + 8*(lane>>5) .. +8] as 16 B.
__global__ void wprep_kernel(const float* __restrict__ W, unsigned short* __restrict__ Wf) {
    int tid = blockIdx.x * blockDim.x + threadIdx.x;   // 0..32767
    int jt  = tid >> 11;
    int rem = tid & 2047;
    int ks  = rem >> 6;
    int L   = rem & 63;
    int j   = jt * 32 + (L & 31);
    int k   = ks * 16 + (L >> 5) * 8;
    const float* src = W + j * DIM + k;
    uint4 p;
    p.x = (unsigned)f2bf(src[0]) | ((unsigned)f2bf(src[1]) << 16);
    p.y = (unsigned)f2bf(src[2]) | ((unsigned)f2bf(src[3]) << 16);
    p.z = (unsigned)f2bf(src[4]) | ((unsigned)f2bf(src[5]) << 16);
    p.w = (unsigned)f2bf(src[6]) | ((unsigned)f2bf(src[7]) << 16);
    ((uint4*)Wf)[tid] = p;
}

__global__ __launch_bounds__(512, 1)
void fixpoint_kernel(const float* __restrict__ x,
                     const unsigned short* __restrict__ Wf,
                     float* __restrict__ out) {
    __shared__ alignas(16) unsigned short zt[TM * DIM];   // 64 KB, single buffer

    const int tid  = threadIdx.x;
    const int lane = tid & 63;
    const int w    = tid >> 6;        // wave 0..7, owns j-slab [64w, 64w+64)
    const int l31  = lane & 31;
    const int h    = lane >> 5;
    const int r0   = blockIdx.x * TM;

    // ---- iteration 1: z = tanh(x) into zt (B-fragment layout) ----
#pragma unroll
    for (int rt = 0; rt < 2; ++rt) {
        const float* xrow = x + (size_t)(r0 + rt * 32 + l31) * DIM;
#pragma unroll
        for (int t = 0; t < 8; ++t) {
            int j0 = w * 64 + (t >> 2) * 32 + (t & 3) * 8 + 4 * h;
            float4 v = *(const float4*)&xrow[j0];
            float v0 = tanh_e(v.x * L2E2), v1 = tanh_e(v.y * L2E2);
            float v2 = tanh_e(v.z * L2E2), v3 = tanh_e(v.w * L2E2);
            uint2 p;
            p.x = ((unsigned)f2bf(v1) << 16) | f2bf(v0);
            p.y = ((unsigned)f2bf(v3) << 16) | f2bf(v2);
            int e = ((rt * 32 + (j0 >> 4)) * 64 + ((j0 >> 3) & 1) * 32 + l31) * 8 + (j0 & 7);
            *(uint2*)&zt[e] = p;
        }
    }
    __syncthreads();

    const s8v* zcv = (const s8v*)zt + lane;

    // Opaque zero offsets: redefined by empty asm every iteration so the
    // compiler cannot hoist the loop-invariant Wf/x loads out of the
    // iteration loop (which would blow up VGPR pressure and spill).
    size_t woff = 0;   // s8v-granule offset into Wf
    size_t xoff = 0;   // float offset into x

#pragma unroll 1
    for (int it = 0; it < NITER - 1; ++it) {
        asm volatile("" : "+s"(woff), "+s"(xoff));
        const s8v*   Wv = (const s8v*)Wf + woff + w * 4096 + lane;
        const float* xp = x + xoff;

        f32x16 acc00 = zero16(), acc01 = zero16(), acc10 = zero16(), acc11 = zero16();

#pragma unroll
        for (int ks = 0; ks < 32; ++ks) {
            s8v a0 = Wv[ks * 64];          // W rows [64w,64w+32)
            s8v a1 = Wv[ks * 64 + 2048];   // W rows [64w+32,64w+64)
            s8v b0 = zcv[ks * 64];         // z rows 0..31
            s8v b1 = zcv[ks * 64 + 2048];  // z rows 32..63
            acc00 = __builtin_amdgcn_mfma_f32_32x32x16_bf16(a0, b0, acc00, 0, 0, 0);
            acc01 = __builtin_amdgcn_mfma_f32_32x32x16_bf16(a0, b1, acc01, 0, 0, 0);
            acc10 = __builtin_amdgcn_mfma_f32_32x32x16_bf16(a1, b0, acc10, 0, 0, 0);
            acc11 = __builtin_amdgcn_mfma_f32_32x32x16_bf16(a1, b1, acc11, 0, 0, 0);
        }

        __syncthreads();   // all waves done READING zt

        const bool last = (it == NITER - 2);

        // D[m=j][n=r]: col = lane&31 -> z-row; row = (reg&3)+8*(reg>>2)+4*h -> j
        auto epi = [&](const f32x16& acc, int tb, int rt) {
            const size_t rowoff = (size_t)(r0 + rt * 32 + l31) * DIM;
#pragma unroll
            for (int g = 0; g < 4; ++g) {
                int j0 = w * 64 + tb * 8 + g * 8 + 4 * h;
                const float4 xv = *(const float4*)&xp[rowoff + j0];
                float v0 = tanh_e((acc[4 * g + 0] + xv.x) * L2E2);
                float v1 = tanh_e((acc[4 * g + 1] + xv.y) * L2E2);
                float v2 = tanh_e((acc[4 * g + 2] + xv.z) * L2E2);
                float v3 = tanh_e((acc[4 * g + 3] + xv.w) * L2E2);
                uint2 p;
                p.x = ((unsigned)f2bf(v1) << 16) | f2bf(v0);
                p.y = ((unsigned)f2bf(v3) << 16) | f2bf(v2);
                int e = ((rt * 32 + (j0 >> 4)) * 64 + ((j0 >> 3) & 1) * 32 + l31) * 8 + (j0 & 7);
                *(uint2*)&zt[e] = p;
                if (last) {
                    float4 o; o.x = v0; o.y = v1; o.z = v2; o.w = v3;
                    *(float4*)&out[rowoff + j0] = o;
                }
            }
        };
        epi(acc00, 0, 0);
        epi(acc10, 4, 0);
        epi(acc01, 0, 1);
        epi(acc11, 4, 1);

        __syncthreads();   // writes visible before next iteration's reads
    }
}

extern "C" void kernel_launch(void* const* d_in, const int* in_sizes, int n_in,
                              void* d_out, int out_size, void* d_ws, size_t ws_size,
                              hipStream_t stream) {
    const float* x = (const float*)d_in[0];   // [16384, 512] fp32
    const float* W = (const float*)d_in[1];   // [512, 512] fp32
    float* out = (float*)d_out;               // [16384, 512] fp32
    unsigned short* Wf = (unsigned short*)d_ws;

    wprep_kernel<<<128, 256, 0, stream>>>(W, Wf);
    fixpoint_kernel<<<BATCH / TM, 512, 0, stream>>>(x, Wf, out);
}